// Round 20
// baseline (157.317 us; speedup 1.0000x reference)
//
#include <hip/hip_runtime.h>
#include <stdint.h>

typedef __bf16 bf16x8 __attribute__((ext_vector_type(8)));
typedef float f32x16 __attribute__((ext_vector_type(16)));

#define NSAMPLE 64
static constexpr int Bb = 4, Nn = 16384, Mm = 1024, Cc = 256;
static constexpr int K1P = 288;   // layer-1 K: 256 features + 3 coords + pad (9 x 32)

__device__ __forceinline__ unsigned short f2bf(float f) {
  unsigned int u = __builtin_bit_cast(unsigned int, f);
  u = u + 0x7fffu + ((u >> 16) & 1u);
  return (unsigned short)(u >> 16);
}

// async global->LDS, 16B per lane; LDS dest = wave-uniform base + lane*16
__device__ __forceinline__ void gload_lds16(const void* g, void* lds) {
  __builtin_amdgcn_global_load_lds(
      (const __attribute__((address_space(1))) uint32_t*)g,
      (__attribute__((address_space(3))) uint32_t*)lds, 16, 0, 0);
}

// ---- ALL helpers in ONE kernel, block-range partitioned (R19 verbatim) ----
__global__ void helpers_kernel(const float* __restrict__ xyz,
                               const float* __restrict__ new_xyz,
                               const float* __restrict__ feats,
                               const float* __restrict__ W1, const float* __restrict__ b1,
                               const float* __restrict__ g1, const float* __restrict__ be1,
                               const float* __restrict__ m1, const float* __restrict__ v1,
                               const float* __restrict__ W2, const float* __restrict__ b2,
                               const float* __restrict__ g2, const float* __restrict__ be2,
                               const float* __restrict__ m2, const float* __restrict__ v2,
                               unsigned short* __restrict__ W1b, float* __restrict__ b1e,
                               unsigned short* __restrict__ W2b, float* __restrict__ b2e,
                               unsigned short* __restrict__ featsT,
                               int* __restrict__ idx) {
  __shared__ float tile[64][65];
  __shared__ int wl[4][4][64];   // [query][wave][slot]
  __shared__ int wcnt[4][4];     // [query][wave]
  int bx = blockIdx.x;
  int t = threadIdx.x;
  if (bx < 1024) {
    const float r2 = (float)(0.08 * 0.08);
    int bm0 = bx * 4;            // queries bm0..bm0+3, same batch (4 | 1024)
    int lane = t & 63, w = t >> 6;
    int b = bm0 >> 10;
    float qx[4], qy[4], qz[4], qq[4];
    int cnt[4];
#pragma unroll
    for (int qi = 0; qi < 4; qi++) {
      qx[qi] = new_xyz[(bm0 + qi) * 3];
      qy[qi] = new_xyz[(bm0 + qi) * 3 + 1];
      qz[qi] = new_xyz[(bm0 + qi) * 3 + 2];
      qq[qi] = __fadd_rn(__fadd_rn(__fmul_rn(qx[qi], qx[qi]), __fmul_rn(qy[qi], qy[qi])),
                         __fmul_rn(qz[qi], qz[qi]));
      cnt[qi] = 0;
    }
    const float* P = xyz + ((size_t)b * Nn + w * 4096) * 3;
    for (int n0 = 0; n0 < 4096; n0 += 64) {
      const float* pp = P + (n0 + lane) * 3;
      float x = pp[0], y = pp[1], z = pp[2];
      float p2 = __fadd_rn(__fadd_rn(__fmul_rn(x, x), __fmul_rn(y, y)), __fmul_rn(z, z));
#pragma unroll
      for (int qi = 0; qi < 4; qi++) {
        if (cnt[qi] >= NSAMPLE) continue;   // wave-uniform
        float dt = __fadd_rn(__fadd_rn(__fmul_rn(qx[qi], x), __fmul_rn(qy[qi], y)),
                             __fmul_rn(qz[qi], z));
        float d2 = __fsub_rn(__fadd_rn(qq[qi], p2), __fmul_rn(2.f, dt));
        bool valid = d2 < r2;
        unsigned long long mask = __ballot(valid);
        if (mask) {
          if (valid) {
            int pos = cnt[qi] + __popcll(mask & ((1ull << lane) - 1ull));
            if (pos < NSAMPLE) wl[qi][w][pos] = w * 4096 + n0 + lane;
          }
          cnt[qi] += (int)__popcll(mask);
        }
      }
      if (cnt[0] >= NSAMPLE && cnt[1] >= NSAMPLE && cnt[2] >= NSAMPLE && cnt[3] >= NSAMPLE)
        break;
    }
    if (lane == 0) {
#pragma unroll
      for (int qi = 0; qi < 4; qi++) wcnt[qi][w] = cnt[qi];
    }
    __syncthreads();
    {
      int qi = t >> 6, s = t & 63;
      int c0 = wcnt[qi][0], c1 = wcnt[qi][1], c2 = wcnt[qi][2], c3 = wcnt[qi][3];
      int tot = c0 + c1 + c2 + c3;
      int cc = tot < NSAMPLE ? tot : NSAMPLE;
      int v;
      if (s < cc) {
        if (s < c0) v = wl[qi][0][s];
        else if (s < c0 + c1) v = wl[qi][1][s - c0];
        else if (s < c0 + c1 + c2) v = wl[qi][2][s - c0 - c1];
        else v = wl[qi][3][s - c0 - c1 - c2];
      } else {
        v = (c0 > 0) ? wl[qi][0][0] : (c1 > 0) ? wl[qi][1][0]
          : (c2 > 0) ? wl[qi][2][0] : (c3 > 0) ? wl[qi][3][0] : 0;
      }
      idx[(size_t)(bm0 + qi) * NSAMPLE + s] = v;
    }
    return;
  }
  if (bx < 5120) {
    // ---------------- featsT — R8 verbatim body ----------------
    int fb = bx - 1024;             // 0..4095
    int b = fb >> 10;
    int rem = fb & 1023;
    int nt = rem >> 2, ct = rem & 3;
    int tx = t & 63, ty = t >> 6;
    const float* src = feats + ((size_t)b * Cc + ct * 64) * Nn + nt * 64;
#pragma unroll
    for (int i = 0; i < 16; i++) {
      int c = i * 4 + ty;
      tile[c][tx] = src[(size_t)c * Nn + tx];
    }
    __syncthreads();
    unsigned short* dst = featsT + ((size_t)b * Nn + nt * 64) * Cc + ct * 64;
    int c4 = (t & 15) * 4, n0 = t >> 4;
#pragma unroll
    for (int i = 0; i < 4; i++) {
      int n = i * 16 + n0;
      ushort4 v;
      v.x = f2bf(tile[c4][n]);
      v.y = f2bf(tile[c4 + 1][n]);
      v.z = f2bf(tile[c4 + 2][n]);
      v.w = f2bf(tile[c4 + 3][n]);
      *(ushort4*)&dst[(size_t)n * Cc + c4] = v;
    }
    return;
  }
  // ---------------- prep body (R1 verbatim) ----------------
  int g = (bx - 5120) * 256 + t;
  if (g < 256 * K1P) {
    int o = g / K1P, k = g - o * K1P;
    float s = g1[o] / sqrtf(v1[o] + 1e-5f);
    float w = 0.f;
    if (k < 256) w = W1[o * 259 + 3 + k];
    else if (k < 259) w = W1[o * 259 + (k - 256)];
    W1b[g] = f2bf(w * s);
  }
  if (g < 256 * 256) {
    int o = g >> 8;
    float s = g2[o] / sqrtf(v2[o] + 1e-5f);
    W2b[g] = f2bf(W2[g] * s);
  }
  if (g < 256) {
    float s1 = g1[g] / sqrtf(v1[g] + 1e-5f);
    b1e[g] = s1 * (b1[g] - m1[g]) + be1[g];
    float s2 = g2[g] / sqrtf(v2[g] + 1e-5f);
    b2e[g] = s2 * (b2[g] - m2[g]) + be2[g];
  }
}

// ---------------- fused: 32x32x16 MFMA variant --------------------------------------------
// Per wave: 2x2 tiles of 32x32 over its 64x64 output slice. A: row = lane&31 (+32*mi),
// k-group = (lane>>5)*8. B (W, row-major [o][K]): col o = wcol + nj*32 + (lane&31), same
// k-group. C/D: col = lane&31, row = (p&3) + 8*(p>>2) + 4*(lane>>5)  [m74/m101 verified].
// L1 = 17 K-steps (16 feat + 1 coord; coord cols 16..31 are zero-pad -> skipped), L2 = 16.
// 132 MFMA/wave vs 272 for the 16x16 shape. Same swizzled Xf (chunk ^= r&7), same H-alias.
__global__ __launch_bounds__(256, 4) void fused_kernel(
    const unsigned short* __restrict__ featsT, const float* __restrict__ xyz,
    const float* __restrict__ new_xyz, const int* __restrict__ idx,
    const unsigned short* __restrict__ W1b, const float* __restrict__ b1e,
    const unsigned short* __restrict__ W2b, const float* __restrict__ b2e,
    float* __restrict__ out) {
  __shared__ unsigned short Xf[64 * 256];  // 32768 B, swizzled feature tile / H tile
  __shared__ unsigned short Xco[64 * 40];  // 5120 B, coord K-chunk (3 coords + zeros)
  int t = threadIdx.x;
  int wave = t >> 6, lane = t & 63;
  int lrow = lane & 31, khalf = lane >> 5;
  int wcol = wave * 64;
  int bm = blockIdx.x;
  int b = bm >> 10;

  {
    int idxr = idx[(size_t)bm * NSAMPLE + wave * 16 + (lane & 15)];
#pragma unroll
    for (int i = 0; i < 8; i++) {
      int j = wave * 8 + i;                       // row pair 2j, 2j+1
      int iv = __shfl(idxr, 2 * i + (lane >> 5));
      int r7 = (2 * j + (lane >> 5)) & 7;
      int cg = (lane & 31) ^ r7;                  // swizzled global chunk (rule #21)
      gload_lds16(featsT + ((size_t)b * Nn + iv) * Cc + cg * 8, &Xf[j * 512]);
    }
  }
  if (t < 64) {
    int ci = idx[(size_t)bm * NSAMPLE + t];
    const float* pp = xyz + ((size_t)b * Nn + ci) * 3;
    float px = pp[0], py = pp[1], pz = pp[2];
    unsigned int c01 = (unsigned int)f2bf(px - new_xyz[bm * 3])
                     | ((unsigned int)f2bf(py - new_xyz[bm * 3 + 1]) << 16);
    unsigned int c2 = (unsigned int)f2bf(pz - new_xyz[bm * 3 + 2]);
    uint4 v0 = make_uint4(c01, c2, 0u, 0u);
    uint4 z = make_uint4(0u, 0u, 0u, 0u);
    uint4* row = (uint4*)&Xco[t * 40];
    row[0] = v0; row[1] = z; row[2] = z; row[3] = z; row[4] = z;
  }
  __syncthreads();

  // ---- layer 1: ks 0..15 feat (A from Xf swizzled), ks 16 coord (A from Xco) ----
  f32x16 acc[2][2];
#pragma unroll
  for (int mi = 0; mi < 2; mi++)
#pragma unroll
    for (int nj = 0; nj < 2; nj++)
#pragma unroll
      for (int p = 0; p < 16; p++) acc[mi][nj][p] = 0.f;
  {
    bf16x8 w[2][2];
#pragma unroll
    for (int nj = 0; nj < 2; nj++)
      w[0][nj] = *(const bf16x8*)&W1b[(size_t)(wcol + nj * 32 + lrow) * K1P + khalf * 8];
#pragma unroll
    for (int ks = 0; ks < 17; ks++) {
      int cur = ks & 1, nxt = cur ^ 1;
      if (ks < 16) {
#pragma unroll
        for (int nj = 0; nj < 2; nj++)
          w[nxt][nj] = *(const bf16x8*)&W1b[(size_t)(wcol + nj * 32 + lrow) * K1P
                                            + (ks + 1) * 16 + khalf * 8];
      }
      bf16x8 a[2];
#pragma unroll
      for (int mi = 0; mi < 2; mi++) {
        int r = mi * 32 + lrow;
        if (ks < 16) {
          int cs = ((ks * 2 + khalf) ^ (r & 7)) * 8;
          a[mi] = *(const bf16x8*)&Xf[r * 256 + cs];
        } else {
          a[mi] = *(const bf16x8*)&Xco[r * 40 + khalf * 8];
        }
      }
#pragma unroll
      for (int mi = 0; mi < 2; mi++)
#pragma unroll
        for (int nj = 0; nj < 2; nj++)
          acc[mi][nj] =
              __builtin_amdgcn_mfma_f32_32x32x16_bf16(a[mi], w[cur][nj], acc[mi][nj], 0, 0, 0);
    }
  }
  __syncthreads();  // B3: all waves done reading Xf

  // ---- epilogue 1: bias + relu -> H (aliases Xf, swizzled store); 32x32 C/D layout ----
#pragma unroll
  for (int nj = 0; nj < 2; nj++) {
    int o = wcol + nj * 32 + lrow;
    float bb = b1e[o];
#pragma unroll
    for (int mi = 0; mi < 2; mi++)
#pragma unroll
      for (int p = 0; p < 16; p++) {
        int r = mi * 32 + (p & 3) + 8 * (p >> 2) + 4 * khalf;
        float h = fmaxf(acc[mi][nj][p] + bb, 0.f);
        Xf[r * 256 + ((((o >> 3) ^ (r & 7)) << 3) + (o & 7))] = f2bf(h);
      }
  }
  __syncthreads();  // B4: H visible

  // ---- layer 2: 16 K-steps from H (same swizzle) ----
#pragma unroll
  for (int mi = 0; mi < 2; mi++)
#pragma unroll
    for (int nj = 0; nj < 2; nj++)
#pragma unroll
      for (int p = 0; p < 16; p++) acc[mi][nj][p] = 0.f;
  {
    bf16x8 w[2][2];
#pragma unroll
    for (int nj = 0; nj < 2; nj++)
      w[0][nj] = *(const bf16x8*)&W2b[(size_t)(wcol + nj * 32 + lrow) * 256 + khalf * 8];
#pragma unroll
    for (int ks = 0; ks < 16; ks++) {
      int cur = ks & 1, nxt = cur ^ 1;
      if (ks < 15) {
#pragma unroll
        for (int nj = 0; nj < 2; nj++)
          w[nxt][nj] = *(const bf16x8*)&W2b[(size_t)(wcol + nj * 32 + lrow) * 256
                                            + (ks + 1) * 16 + khalf * 8];
      }
      bf16x8 a[2];
#pragma unroll
      for (int mi = 0; mi < 2; mi++) {
        int r = mi * 32 + lrow;
        int cs = ((ks * 2 + khalf) ^ (r & 7)) * 8;
        a[mi] = *(const bf16x8*)&Xf[r * 256 + cs];
      }
#pragma unroll
      for (int mi = 0; mi < 2; mi++)
#pragma unroll
        for (int nj = 0; nj < 2; nj++)
          acc[mi][nj] =
              __builtin_amdgcn_mfma_f32_32x32x16_bf16(a[mi], w[cur][nj], acc[mi][nj], 0, 0, 0);
    }
  }
  // ---- epilogue 2: bias + relu + max over 64 samples -> out[b][o][m] ----
  {
    int m = bm & (Mm - 1);
#pragma unroll
    for (int nj = 0; nj < 2; nj++) {
      int o = wcol + nj * 32 + lrow;
      float bv = b2e[o];
      float v = 0.f;  // relu(max) == max(relu)
#pragma unroll
      for (int mi = 0; mi < 2; mi++)
#pragma unroll
        for (int p = 0; p < 16; p++) v = fmaxf(v, acc[mi][nj][p] + bv);
      v = fmaxf(v, __shfl_xor(v, 32));   // lanes l / l+32 hold complementary row sets
      if (khalf == 0)
        out[((size_t)b * 256 + o) * Mm + m] = v;
    }
  }
}

extern "C" void kernel_launch(void* const* d_in, const int* in_sizes, int n_in,
                              void* d_out, int out_size, void* d_ws, size_t ws_size,
                              hipStream_t stream) {
  (void)in_sizes; (void)n_in; (void)out_size; (void)ws_size;
  const float* xyz     = (const float*)d_in[0];
  const float* new_xyz = (const float*)d_in[1];
  const float* feats   = (const float*)d_in[2];
  const float* W1 = (const float*)d_in[3];
  const float* b1 = (const float*)d_in[4];
  const float* g1 = (const float*)d_in[5];
  const float* be1 = (const float*)d_in[6];
  const float* m1 = (const float*)d_in[7];
  const float* v1 = (const float*)d_in[8];
  const float* W2 = (const float*)d_in[9];
  const float* b2 = (const float*)d_in[10];
  const float* g2 = (const float*)d_in[11];
  const float* be2 = (const float*)d_in[12];
  const float* m2 = (const float*)d_in[13];
  const float* v2 = (const float*)d_in[14];
  float* out = (float*)d_out;

  char* ws = (char*)d_ws;
  unsigned short* W1b   = (unsigned short*)(ws + 0);         // 147456 B ([256][288])
  unsigned short* W2b   = (unsigned short*)(ws + 147456);    // 131072 B
  float*          b1e   = (float*)(ws + 278528);             // 1024 B
  float*          b2e   = (float*)(ws + 279552);             // 1024 B
  unsigned short* featsT= (unsigned short*)(ws + 280576);    // 33554432 B
  int*            idx   = (int*)(ws + 33835008);             // 1048576 B (end ~34.9 MB)

  helpers_kernel<<<1024 + 4096 + 288, 256, 0, stream>>>(
      xyz, new_xyz, feats, W1, b1, g1, be1, m1, v1, W2, b2, g2, be2, m2, v2,
      W1b, b1e, W2b, b2e, featsT, idx);
  fused_kernel<<<Bb * Mm, 256, 0, stream>>>(featsT, xyz, new_xyz, idx,
                                            W1b, b1e, W2b, b2e, out);
}